// Round 9
// baseline (365.256 us; speedup 1.0000x reference)
//
#include <hip/hip_runtime.h>

typedef unsigned long long u64;

#define F_IN 512
#define HID 128
#define CLS 64
#define EPS 1e-5f
#define NSB 512   // col_stats partial blocks

// ============ K1: col_stats ∥ deg ∥ pack_w1 ∥ pack_w2 (all independent) =====
__global__ __launch_bounds__(256) void prep_k(const float4* __restrict__ x4,
                                              float* __restrict__ psum,
                                              float* __restrict__ psq,
                                              int n, int rpb,
                                              const int* __restrict__ col,
                                              int* __restrict__ deg, int e, int nbdeg,
                                              const float* __restrict__ W1,
                                              u64* __restrict__ sig1,
                                              float* __restrict__ beta1,
                                              const float* __restrict__ W2,
                                              ulonglong2* __restrict__ sigw2,
                                              float* __restrict__ beta2) {
    __shared__ float red[256][9];
    int b = blockIdx.x;
    int tid = threadIdx.x;
    if (b < NSB) {
        // ---- column stats partials (no atomics) ----
        int c4 = tid & 127;
        int half = tid >> 7;
        int r0 = b * rpb;
        int r1 = min(n, r0 + rpb);
        float s0=0.f,s1=0.f,s2=0.f,s3=0.f,q0=0.f,q1=0.f,q2=0.f,q3=0.f;
#pragma unroll 4
        for (int r = r0 + half; r < r1; r += 2) {
            float4 v = x4[(size_t)r * 128 + c4];
            s0 += v.x; q0 += v.x * v.x;
            s1 += v.y; q1 += v.y * v.y;
            s2 += v.z; q2 += v.z * v.z;
            s3 += v.w; q3 += v.w * v.w;
        }
        red[tid][0]=s0; red[tid][1]=s1; red[tid][2]=s2; red[tid][3]=s3;
        red[tid][4]=q0; red[tid][5]=q1; red[tid][6]=q2; red[tid][7]=q3;
        __syncthreads();
        if (half == 0) {
            int c = c4 * 4;
            float* os = &psum[(size_t)b * 512 + c];
            float* oq = &psq [(size_t)b * 512 + c];
            os[0] = s0 + red[c4+128][0]; os[1] = s1 + red[c4+128][1];
            os[2] = s2 + red[c4+128][2]; os[3] = s3 + red[c4+128][3];
            oq[0] = q0 + red[c4+128][4]; oq[1] = q1 + red[c4+128][5];
            oq[2] = q2 + red[c4+128][6]; oq[3] = q3 + red[c4+128][7];
        }
    } else if (b < NSB + nbdeg) {
        // ---- degree histogram, 4 edges per thread (int4 loads) ----
        int i4 = (b - NSB) * 256 + tid;
        int base = i4 * 4;
        if (base + 3 < e) {
            int4 cc = *(const int4*)&col[base];
            atomicAdd(&deg[cc.x], 1);
            atomicAdd(&deg[cc.y], 1);
            atomicAdd(&deg[cc.z], 1);
            atomicAdd(&deg[cc.w], 1);
        } else {
            for (int i = base; i < e; ++i) atomicAdd(&deg[col[i]], 1);
        }
    } else if (b < NSB + nbdeg + 32) {
        // ---- pack W1: wave per hidden col j ----
        int wave = tid >> 6, l = tid & 63;
        int j = (b - NSB - nbdeg) * 4 + wave;   // 0..127
        float asum = 0.f;
#pragma unroll
        for (int jw = 0; jw < 8; ++jw) {
            int f = (jw < 4) ? (4*l + jw) : (256 + 4*l + (jw - 4));
            float v = W1[(size_t)f * HID + j];
            asum += fabsf(v);
            u64 bb = __ballot(v > 0.0f);
            if (l == 0) sig1[jw * HID + j] = bb;
        }
        for (int m = 32; m >= 1; m >>= 1) asum += __shfl_xor(asum, m);
        if (l == 0) beta1[j] = asum * (1.0f / 512.0f);
    } else {
        // ---- pack W2: wave per class j; 128-bit signature (even/odd words) --
        int wave = tid >> 6, l = tid & 63;
        int j = (b - NSB - nbdeg - 32) * 4 + wave;   // 0..63
        float v0 = W2[(size_t)(2 * l) * CLS + j];
        float v1 = W2[(size_t)(2 * l + 1) * CLS + j];
        float asum = fabsf(v0) + fabsf(v1);
        u64 s0 = __ballot(v0 > 0.0f);
        u64 s1 = __ballot(v1 > 0.0f);
        for (int m = 32; m >= 1; m >>= 1) asum += __shfl_xor(asum, m);
        if (l == 0) {
            ulonglong2 t; t.x = s0; t.y = s1;
            sigw2[j] = t;
            beta2[j] = asum * (1.0f / 128.0f);
        }
    }
}

// ============ K2: stats_reduce ∥ scan_partial ===============================
__global__ __launch_bounds__(256) void mid_k(const float* __restrict__ psum,
                                             const float* __restrict__ psq,
                                             float* __restrict__ mu,
                                             float* __restrict__ rinv, int n,
                                             const int* __restrict__ deg,
                                             int* __restrict__ bsum) {
    __shared__ float reds[256], redq[256];
    __shared__ int lds[256];
    int b = blockIdx.x;
    int t = threadIdx.x;
    if (b < 16) {
        int cc = t & 31;
        int bs = t >> 5;
        int c = b * 32 + cc;
        float s = 0.f, q = 0.f;
#pragma unroll 4
        for (int p = bs; p < NSB; p += 8) {
            s += psum[(size_t)p * 512 + c];
            q += psq [(size_t)p * 512 + c];
        }
        reds[t] = s; redq[t] = q;
        __syncthreads();
        if (bs == 0) {
#pragma unroll
            for (int u = 1; u < 8; ++u) { s += reds[cc + 32*u]; q += redq[cc + 32*u]; }
            float m = s / (float)n;
            float v = q / (float)n - m * m;
            mu[c] = m;
            rinv[c] = rsqrtf(v + EPS);
        }
    } else {
        int blk = b - 16;
        int i = blk * 256 + t;
        lds[t] = (i < n) ? deg[i] : 0;
        __syncthreads();
        for (int s = 128; s > 0; s >>= 1) {
            if (t < s) lds[t] += lds[t + s];
            __syncthreads();
        }
        if (t == 0) bsum[blk] = lds[0];
    }
}

__global__ __launch_bounds__(256) void scan_bsum_k(const int* __restrict__ bsum,
                                                   int* __restrict__ boff, int nb) {
    __shared__ int lds[256];
    int t = threadIdx.x;
    int v = (t < nb) ? bsum[t] : 0;
    lds[t] = v;
    __syncthreads();
    for (int s = 1; s < 256; s <<= 1) {
        int add = (t >= s) ? lds[t - s] : 0;
        __syncthreads();
        lds[t] += add;
        __syncthreads();
    }
    if (t < nb) boff[t] = lds[t] - v;   // exclusive
}

__global__ __launch_bounds__(256) void scan_final_k(const int* __restrict__ deg,
                                                    const int* __restrict__ boff,
                                                    int* __restrict__ offs,
                                                    int* __restrict__ cursor,
                                                    float* __restrict__ dinv, int n) {
    __shared__ int lds[256];
    int t = threadIdx.x;
    int i = blockIdx.x * 256 + t;
    int v = (i < n) ? deg[i] : 0;
    lds[t] = v;
    __syncthreads();
    for (int s = 1; s < 256; s <<= 1) {
        int add = (t >= s) ? lds[t - s] : 0;
        __syncthreads();
        lds[t] += add;
        __syncthreads();
    }
    int excl = lds[t] - v + boff[blockIdx.x];
    if (i < n) {
        offs[i] = excl; cursor[i] = excl;
        dinv[i] = rsqrtf((float)v + 1.0f);   // +1 self-loop
    } else if (i == n) {
        offs[n] = excl;                      // sentinel: total edges
    }
}

// ============ K5: bin1_gemm1 (writes pa1 = dinv*a1) ∥ fill (4B entries) =====
__global__ __launch_bounds__(256) void main1_k(const float4* __restrict__ x4,
                                               const float4* __restrict__ mu4,
                                               const float4* __restrict__ rinv4,
                                               const u64* __restrict__ sigW,
                                               const float* __restrict__ dinv,
                                               float* __restrict__ pa1,
                                               short2* __restrict__ dots, int n, int nbin,
                                               const int* __restrict__ row,
                                               const int* __restrict__ col,
                                               int* __restrict__ cursor,
                                               int* __restrict__ csr, int e) {
    int b = blockIdx.x;
    int tid = threadIdx.x;
    if (b < nbin) {
        // ---- layer 1: binarize + XNOR popcount GEMM ----
        int wave = tid >> 6, l = tid & 63;
        int i = b * 4 + wave;
        if (i >= n) return;
        const float4* xr = x4 + (size_t)i * 128;
        float4 va = xr[l], vb = xr[64 + l];
        float4 ma = mu4[l], mb = mu4[64 + l];
        float4 ra = rinv4[l], rb = rinv4[64 + l];
        float t0 = va.x - ma.x, t1 = va.y - ma.y, t2 = va.z - ma.z, t3 = va.w - ma.w;
        float t4 = vb.x - mb.x, t5 = vb.y - mb.y, t6 = vb.z - mb.z, t7 = vb.w - mb.w;
        float asum = fabsf(t0)*ra.x + fabsf(t1)*ra.y + fabsf(t2)*ra.z + fabsf(t3)*ra.w
                   + fabsf(t4)*rb.x + fabsf(t5)*rb.y + fabsf(t6)*rb.z + fabsf(t7)*rb.w;
        u64 sx[8];
        sx[0] = __ballot(t0 > 0.f); sx[1] = __ballot(t1 > 0.f);
        sx[2] = __ballot(t2 > 0.f); sx[3] = __ballot(t3 > 0.f);
        sx[4] = __ballot(t4 > 0.f); sx[5] = __ballot(t5 > 0.f);
        sx[6] = __ballot(t6 > 0.f); sx[7] = __ballot(t7 > 0.f);
        for (int m = 32; m >= 1; m >>= 1) asum += __shfl_xor(asum, m);
        if (l == 0) pa1[i] = dinv[i] * asum * (1.0f / 512.0f);
        int c0 = 0, c1 = 0;
#pragma unroll
        for (int w = 0; w < 8; ++w) {
            c0 += __popcll(sx[w] ^ sigW[w * HID + 2*l]);
            c1 += __popcll(sx[w] ^ sigW[w * HID + 2*l + 1]);
        }
        dots[(size_t)i * 64 + l] = make_short2((short)(512 - 2*c0), (short)(512 - 2*c1));
    } else {
        // ---- CSR fill: 4 edges per thread, 4B entries ----
        int i4 = (b - nbin) * 256 + tid;
        int base = i4 * 4;
        if (base + 3 < e) {
            int4 rr = *(const int4*)&row[base];
            int4 cc = *(const int4*)&col[base];
            csr[atomicAdd(&cursor[cc.x], 1)] = rr.x;
            csr[atomicAdd(&cursor[cc.y], 1)] = rr.y;
            csr[atomicAdd(&cursor[cc.z], 1)] = rr.z;
            csr[atomicAdd(&cursor[cc.w], 1)] = rr.w;
        } else {
            for (int i = base; i < e; ++i)
                csr[atomicAdd(&cursor[col[i]], 1)] = row[i];
        }
    }
}

// ============ K6: agg layer1 (gather pa1/dots, unroll 8) -> sig2x, pa2 ======
__global__ __launch_bounds__(256) void agg1_fused_k(const short2* __restrict__ dots,
                                                    const float* __restrict__ pa1,
                                                    const int* __restrict__ csr,
                                                    const int* __restrict__ offs,
                                                    const float* __restrict__ dinv,
                                                    const float2* __restrict__ beta1_2,
                                                    const float2* __restrict__ b1_2,
                                                    u64* __restrict__ sig2x,
                                                    float* __restrict__ pa2, int n) {
    int tid = threadIdx.x;
    int wave = tid >> 6, l = tid & 63;
    int i = blockIdx.x * 4 + wave;
    if (i >= n) return;
    float di = dinv[i];
    short2 ds = dots[(size_t)i * 64 + l];
    float p_i = pa1[i];
    float acc0 = p_i * (float)ds.x;       // di factored out of the whole sum
    float acc1 = p_i * (float)ds.y;
    int off = offs[i];
    int d = offs[i + 1] - off;
    int k = 0;
    for (; k + 8 <= d; k += 8) {
        int rr[8]; float tt[8]; short2 dd[8];
#pragma unroll
        for (int u = 0; u < 8; ++u) rr[u] = csr[off + k + u];
#pragma unroll
        for (int u = 0; u < 8; ++u) tt[u] = pa1[rr[u]];
#pragma unroll
        for (int u = 0; u < 8; ++u) dd[u] = dots[(size_t)rr[u] * 64 + l];
#pragma unroll
        for (int u = 0; u < 8; ++u) {
            acc0 += tt[u] * (float)dd[u].x;
            acc1 += tt[u] * (float)dd[u].y;
        }
    }
    for (; k < d; ++k) {
        int r = csr[off + k];
        float t = pa1[r];
        short2 dv = dots[(size_t)r * 64 + l];
        acc0 += t * (float)dv.x;
        acc1 += t * (float)dv.y;
    }
    float2 be = beta1_2[l], bb = b1_2[l];
    acc0 = be.x * (di * acc0) + bb.x;     // hidden features 2l, 2l+1
    acc1 = be.y * (di * acc1) + bb.y;
    float asum = fabsf(acc0) + fabsf(acc1);
    for (int m = 32; m >= 1; m >>= 1) asum += __shfl_xor(asum, m);
    u64 s0 = __ballot(acc0 > 0.f);        // even features
    u64 s1 = __ballot(acc1 > 0.f);        // odd features
    if (l == 0) {
        ulonglong2 pk; pk.x = s0; pk.y = s1;
        *(ulonglong2*)&sig2x[2 * (size_t)i] = pk;
        pa2[i] = di * asum * (1.0f / 128.0f);
    }
}

// ============ K7: agg layer2 popcount domain (unroll 8) + log_softmax =======
__global__ __launch_bounds__(256) void agg2_pop_k(const u64* __restrict__ sig2x,
                                                  const float* __restrict__ pa2,
                                                  const int* __restrict__ csr,
                                                  const int* __restrict__ offs,
                                                  const float* __restrict__ dinv,
                                                  const ulonglong2* __restrict__ sigw2,
                                                  const float* __restrict__ beta2,
                                                  const float* __restrict__ b2,
                                                  float* __restrict__ out, int n) {
    int tid = threadIdx.x;
    int wave = tid >> 6, l = tid & 63;
    int i = blockIdx.x * 4 + wave;
    if (i >= n) return;
    ulonglong2 wsig = sigw2[l];           // this lane's class signature
    float bet = beta2[l], bias = b2[l];
    float di = dinv[i];
    float p_i = pa2[i];
    ulonglong2 ss = *(const ulonglong2*)&sig2x[2 * (size_t)i];
    int dp = __popcll(ss.x ^ wsig.x) + __popcll(ss.y ^ wsig.y);
    float acc = p_i * (float)(128 - 2 * dp);
    int off = offs[i];
    int d = offs[i + 1] - off;
    int k = 0;
    for (; k + 8 <= d; k += 8) {
        int rr[8]; float tt[8]; ulonglong2 gg[8];
#pragma unroll
        for (int u = 0; u < 8; ++u) rr[u] = csr[off + k + u];
#pragma unroll
        for (int u = 0; u < 8; ++u) tt[u] = pa2[rr[u]];
#pragma unroll
        for (int u = 0; u < 8; ++u) gg[u] = *(const ulonglong2*)&sig2x[2 * (size_t)rr[u]];
#pragma unroll
        for (int u = 0; u < 8; ++u) {
            int p = __popcll(gg[u].x ^ wsig.x) + __popcll(gg[u].y ^ wsig.y);
            acc += tt[u] * (float)(128 - 2 * p);
        }
    }
    for (; k < d; ++k) {
        int r = csr[off + k];
        ulonglong2 gs = *(const ulonglong2*)&sig2x[2 * (size_t)r];
        float t = pa2[r];
        int p = __popcll(gs.x ^ wsig.x) + __popcll(gs.y ^ wsig.y);
        acc += t * (float)(128 - 2 * p);
    }
    float o = bet * (di * acc) + bias;
    // log_softmax over 64 classes (one per lane)
    float m = o;
    for (int k2 = 32; k2 >= 1; k2 >>= 1) m = fmaxf(m, __shfl_xor(m, k2));
    float ev = __expf(o - m);
    float s = ev;
    for (int k2 = 32; k2 >= 1; k2 >>= 1) s += __shfl_xor(s, k2);
    out[(size_t)i * CLS + l] = o - m - __logf(s);
}

// ---------------- launch ----------------
extern "C" void kernel_launch(void* const* d_in, const int* in_sizes, int n_in,
                              void* d_out, int out_size, void* d_ws, size_t ws_size,
                              hipStream_t stream) {
    const float* x  = (const float*)d_in[0];
    const int*   ei = (const int*)d_in[1];
    const float* W1 = (const float*)d_in[2];
    const float* b1 = (const float*)d_in[3];
    const float* W2 = (const float*)d_in[4];
    const float* b2 = (const float*)d_in[5];
    float* out = (float*)d_out;

    const int n = in_sizes[0] / F_IN;   // 50000
    const int e = in_sizes[1] / 2;      // 800000
    const int* row = ei;
    const int* col = ei + e;

    // ---- workspace bump allocator (256B aligned) ----
    char* w = (char*)d_ws;
    size_t off = 0;
    auto alloc = [&](size_t bytes) {
        void* p = w + off;
        off += (bytes + 255) & ~(size_t)255;
        return p;
    };
    int*   deg    = (int*)alloc((size_t)n * 4);     // zeroed
    size_t zero_bytes = off;
    float* psum   = (float*)alloc((size_t)NSB * 512 * 4);
    float* psq    = (float*)alloc((size_t)NSB * 512 * 4);
    float* mu     = (float*)alloc(F_IN * 4);
    float* rinv   = (float*)alloc(F_IN * 4);
    float* dinv   = (float*)alloc((size_t)n * 4);
    float* beta1  = (float*)alloc(HID * 4);
    u64*   sig1   = (u64*)alloc(HID * 8 * 8);
    ulonglong2* sigw2 = (ulonglong2*)alloc(CLS * 16);
    float* beta2  = (float*)alloc(CLS * 4);
    int*   offs   = (int*)alloc(((size_t)n + 1) * 4);
    int*   cursor = (int*)alloc((size_t)n * 4);
    int*   bsum   = (int*)alloc(256 * 4);
    int*   boff   = (int*)alloc(256 * 4);
    int*   csr    = (int*)alloc((size_t)e * 4);
    short2* dots  = (short2*)alloc((size_t)n * 64 * 4);
    float* pa1    = (float*)alloc((size_t)n * 4);
    u64*   sig2x  = (u64*)alloc((size_t)n * 2 * 8);
    float* pa2    = (float*)alloc((size_t)n * 4);
    (void)ws_size;

    hipMemsetAsync(deg, 0, zero_bytes, stream);

    int rpb = (n + NSB - 1) / NSB;          // 98
    int e4 = (e + 3) / 4;
    int nbdeg = (e4 + 255) / 256;           // 782
    int nb = (n + 255) / 256;               // 196
    int nbin = (n + 3) / 4;                 // 12500

    // K1: col_stats ∥ deg ∥ pack_w1 ∥ pack_w2
    prep_k<<<NSB + nbdeg + 32 + 16, 256, 0, stream>>>(
        (const float4*)x, psum, psq, n, rpb,
        col, deg, e, nbdeg,
        W1, sig1, beta1, W2, sigw2, beta2);

    // K2: stats_reduce ∥ scan_partial
    mid_k<<<16 + nb, 256, 0, stream>>>(psum, psq, mu, rinv, n, deg, bsum);
    scan_bsum_k<<<1, 256, 0, stream>>>(bsum, boff, nb);
    scan_final_k<<<nb, 256, 0, stream>>>(deg, boff, offs, cursor, dinv, n);

    // K5: bin1 ∥ fill
    main1_k<<<nbin + nbdeg, 256, 0, stream>>>(
        (const float4*)x, (const float4*)mu, (const float4*)rinv, sig1,
        dinv, pa1, dots, n, nbin,
        row, col, cursor, csr, e);

    agg1_fused_k<<<nbin, 256, 0, stream>>>(dots, pa1, csr, offs, dinv,
                                           (const float2*)beta1, (const float2*)b1,
                                           sig2x, pa2, n);
    agg2_pop_k<<<nbin, 256, 0, stream>>>(sig2x, pa2, csr, offs, dinv,
                                         sigw2, beta2, b2, out, n);
}